// Round 3
// baseline (505.366 us; speedup 1.0000x reference)
//
#include <hip/hip_runtime.h>

#define CIN 61
constexpr float EPS = 1e-5f;
constexpr double SCALE = 16777216.0;  // 2^24 fixed-point deterministic stat sums

using s16x8 = __attribute__((ext_vector_type(8))) short;
using fx4   = __attribute__((ext_vector_type(4))) float;

static __device__ __forceinline__ unsigned short f2bf(float f) {
  unsigned int u = __float_as_uint(f);
  u = (u + 0x7fffu + ((u >> 16) & 1u)) >> 16;
  return (unsigned short)u;
}
static __device__ __forceinline__ float bf2f(unsigned short h) {
  return __uint_as_float(((unsigned int)h) << 16);
}

__device__ __forceinline__ void stat_reduce(float val, float* red, long long* dst_ll) {
  int tid = threadIdx.x;
  red[tid] = val;
  __syncthreads();
  if (tid < 64) {
    float t = red[tid] + red[tid + 64] + red[tid + 128] + red[tid + 192];
    atomicAdd((unsigned long long*)&dst_ll[tid],
              (unsigned long long)(long long)((double)t * SCALE));
  }
  __syncthreads();
}

// ---- node GEMV: y = bf16(x @ W1[:61] + b1) ----
__global__ __launch_bounds__(256) void k_y(
    const float* __restrict__ x, const float* __restrict__ W1,
    const float* __restrict__ b1, unsigned short* __restrict__ y, int N) {
  const int tid = threadIdx.x, lane = tid & 63, wv = tid >> 6;
  float w[64];
#pragma unroll
  for (int k = 0; k < 64; ++k) w[k] = (k < CIN) ? W1[k * 64 + lane] : 0.f;
  const float bv = b1[lane];
  __shared__ float lrow[4][64];
  const int nq = N >> 2;
  for (int q = blockIdx.x; q < nq; q += gridDim.x) {
    const int n = (q << 2) + wv;
    lrow[wv][lane] = (lane < CIN) ? x[n * CIN + lane] : 0.f;
    __syncthreads();
    float a0 = bv, a1 = 0.f, a2 = 0.f, a3 = 0.f;
    const float4* rr = (const float4*)&lrow[wv][0];
#pragma unroll
    for (int k4 = 0; k4 < 16; ++k4) {
      float4 v = rr[k4];
      a0 = fmaf(v.x, w[4 * k4 + 0], a0);
      a1 = fmaf(v.y, w[4 * k4 + 1], a1);
      a2 = fmaf(v.z, w[4 * k4 + 2], a2);
      a3 = fmaf(v.w, w[4 * k4 + 3], a3);
    }
    y[(size_t)n * 64 + lane] = f2bf((a0 + a1) + (a2 + a3));
    __syncthreads();
  }
}

// ---- shortcut GEMV: s = x @ Ws + bs (f32) + stats over N ----
__global__ __launch_bounds__(256) void k_short(
    const float* __restrict__ x, const float* __restrict__ Ws,
    const float* __restrict__ bs, float* __restrict__ s_out,
    long long* __restrict__ stats, int N) {
  const int tid = threadIdx.x, lane = tid & 63, wv = tid >> 6;
  float w[64];
#pragma unroll
  for (int k = 0; k < 64; ++k) w[k] = (k < CIN) ? Ws[k * 64 + lane] : 0.f;
  const float bv = bs[lane];
  __shared__ float lrow[4][64];
  __shared__ float red[256];
  float ssum = 0.f, ssq = 0.f;
  const int nq = N >> 2;
  for (int q = blockIdx.x; q < nq; q += gridDim.x) {
    const int n = (q << 2) + wv;
    lrow[wv][lane] = (lane < CIN) ? x[n * CIN + lane] : 0.f;
    __syncthreads();
    float a0 = bv, a1 = 0.f, a2 = 0.f, a3 = 0.f;
    const float4* rr = (const float4*)&lrow[wv][0];
#pragma unroll
    for (int k4 = 0; k4 < 16; ++k4) {
      float4 v = rr[k4];
      a0 = fmaf(v.x, w[4 * k4 + 0], a0);
      a1 = fmaf(v.y, w[4 * k4 + 1], a1);
      a2 = fmaf(v.z, w[4 * k4 + 2], a2);
      a3 = fmaf(v.w, w[4 * k4 + 3], a3);
    }
    const float acc = (a0 + a1) + (a2 + a3);
    s_out[(size_t)n * 64 + lane] = acc;
    ssum += acc;
    ssq = fmaf(acc, acc, ssq);
    __syncthreads();
  }
  stat_reduce(ssum, red, stats + 256);
  stat_reduce(ssq, red, stats + 320);
}

// ---- histogram of dst ----
__global__ __launch_bounds__(256) void k_hist(
    const int* __restrict__ ei, unsigned int* __restrict__ hist, int E) {
  int i = blockIdx.x * 256 + threadIdx.x;
  const int st = gridDim.x * 256;
  for (; i < E; i += st) atomicAdd(&hist[ei[E + i]], 1u);
}

// ---- single-block exclusive scan of hist -> cursor ----
__global__ __launch_bounds__(1024) void k_scan(
    const unsigned int* __restrict__ hist, unsigned int* __restrict__ cursor, int n) {
  const int tid = threadIdx.x;
  const int per = (n + 1023) / 1024;
  const int lo = tid * per;
  const int hi = (lo + per < n) ? lo + per : n;
  unsigned int tot = 0;
  for (int i = lo; i < hi; ++i) tot += hist[i];
  const int lane = tid & 63, w = tid >> 6;
  unsigned int incl = tot;
#pragma unroll
  for (int off = 1; off < 64; off <<= 1) {
    unsigned int t = __shfl_up(incl, off);
    if (lane >= off) incl += t;
  }
  __shared__ unsigned int wsum[16];
  if (lane == 63) wsum[w] = incl;
  __syncthreads();
  unsigned int wbase = 0;
#pragma unroll
  for (int k = 0; k < 16; ++k) wbase += (k < w) ? wsum[k] : 0u;
  unsigned int run = wbase + incl - tot;  // exclusive prefix at lo
  for (int i = lo; i < hi; ++i) {
    unsigned int h = hist[i];
    cursor[i] = run;
    run += h;
  }
}

// ---- edge pass 1: t1 stats (no store) + counting-sort scatter of edge ids ----
__global__ __launch_bounds__(256) void k_edge1(
    const int* __restrict__ ei, const float* __restrict__ pos,
    const unsigned short* __restrict__ y, const float* __restrict__ W1,
    unsigned int* __restrict__ cursor, unsigned int* __restrict__ perm,
    long long* __restrict__ stats, int E) {
  const int tid = threadIdx.x, lane = tid & 63, wv = tid >> 6;
  const float wp0 = W1[61 * 64 + lane];
  const float wp1 = W1[62 * 64 + lane];
  const float wp2 = W1[63 * 64 + lane];
  float ssum = 0.f, ssq = 0.f;
  const int wid = blockIdx.x * 4 + wv, nw = gridDim.x * 4;
  for (int e = wid; e < E; e += nw) {
    const int src = ei[e], dst = ei[E + e];
    float pv = 0.f;
    if (lane < 3) pv = pos[src * 3 + lane] - pos[dst * 3 + lane];
    const float p0 = __shfl(pv, 0), p1 = __shfl(pv, 1), p2 = __shfl(pv, 2);
    float t = bf2f(y[(size_t)src * 64 + lane]);
    t = fmaf(p0, wp0, t);
    t = fmaf(p1, wp1, t);
    t = fmaf(p2, wp2, t);
    t = fmaxf(t, 0.f);
    if (lane == 0) {
      const unsigned int off = atomicAdd(&cursor[dst], 1u);
      perm[off] = (unsigned int)e;
    }
    ssum += t;
    ssq = fmaf(t, t, ssq);
  }
  __shared__ float red[256];
  stat_reduce(ssum, red, stats + 0);
  stat_reduce(ssq, red, stats + 64);
}

// ---- BN coef: a = g*rsqrt(var+eps), c = be - mean*a ----
__global__ void k_coef(const long long* __restrict__ sum,
                       const long long* __restrict__ sq,
                       const float* __restrict__ g, const float* __restrict__ be,
                       float* __restrict__ a_out, float* __restrict__ c_out,
                       double inv) {
  int c = threadIdx.x;
  double m = (double)sum[c] * inv;
  double v = (double)sq[c] * inv - m * m;
  float rs = rsqrtf((float)v + EPS);
  float a = g[c] * rs;
  a_out[c] = a;
  c_out[c] = fmaf(-(float)m, a, be[c]);
}

// ---- fold BN1 affine into W2 ----
__global__ void k_coefW2(const float* __restrict__ W2, const float* __restrict__ b2,
                         const float* __restrict__ coef, unsigned short* __restrict__ W2p,
                         float* __restrict__ b2p) {
  const int c = threadIdx.x;
  float acc = b2[c];
  for (int k = 0; k < 64; ++k) {
    const float w = W2[k * 64 + c];
    acc = fmaf(coef[64 + k], w, acc);
    W2p[k * 64 + c] = f2bf(coef[k] * w);
  }
  b2p[c] = acc;
}

// ---- edge pass 2 (fused, dst-sorted): recompute t1 in frag layout, MFMA,
//      stats, run-segmented scatter-max ----
__global__ __launch_bounds__(256) void k_edge2(
    const unsigned short* __restrict__ y, const int* __restrict__ ei,
    const unsigned int* __restrict__ perm, const float* __restrict__ pos,
    const float* __restrict__ W1, const unsigned short* __restrict__ W2p,
    const float* __restrict__ b2p, long long* __restrict__ stats,
    unsigned int* __restrict__ agg, int E) {
  const int tid = threadIdx.x, lane = tid & 63, wv = tid >> 6;
  const int l15 = lane & 15, lg = lane >> 4;
  s16x8 bF[4][2];
#pragma unroll
  for (int t = 0; t < 4; ++t) {
    const int col = l15 + 16 * t;
#pragma unroll
    for (int s = 0; s < 2; ++s)
#pragma unroll
      for (int i = 0; i < 8; ++i)
        bF[t][s][i] = (short)W2p[(s * 32 + lg * 8 + i) * 64 + col];
  }
  float bias[4];
#pragma unroll
  for (int t = 0; t < 4; ++t) bias[t] = b2p[l15 + 16 * t];
  float wpA[3][8], wpB[3][8];
#pragma unroll
  for (int d = 0; d < 3; ++d)
#pragma unroll
    for (int i = 0; i < 8; ++i) {
      wpA[d][i] = W1[(61 + d) * 64 + lg * 8 + i];
      wpB[d][i] = W1[(61 + d) * 64 + 32 + lg * 8 + i];
    }
  __shared__ float ld2[4][16][64];
  __shared__ int ldd[4][16];
  float ssum[4] = {0.f, 0.f, 0.f, 0.f}, ssq[4] = {0.f, 0.f, 0.f, 0.f};
  const int ntile = E >> 4;
  const int tps = gridDim.x * 4;
  const int nsteps = (ntile + tps - 1) / tps;
  for (int s = 0; s < nsteps; ++s) {
    const int tile = s * tps + blockIdx.x * 4 + wv;
    const bool act = tile < ntile;
    if (act) {
      const int rbase = tile << 4;
      const int eid = (int)perm[rbase + l15];
      const int src = ei[eid];
      const int dstv = ei[E + eid];
      float p[3];
#pragma unroll
      for (int d = 0; d < 3; ++d) p[d] = pos[src * 3 + d] - pos[dstv * 3 + d];
      const unsigned short* yr = y + (size_t)src * 64 + lg * 8;
      const s16x8 y0 = *(const s16x8*)yr;
      const s16x8 y1 = *(const s16x8*)(yr + 32);
      union { s16x8 v; unsigned int u[4]; } a0, a1;
#pragma unroll
      for (int h = 0; h < 4; ++h) {
        float f0 = bf2f((unsigned short)y0[2 * h]);
        float f1 = bf2f((unsigned short)y0[2 * h + 1]);
#pragma unroll
        for (int d = 0; d < 3; ++d) {
          f0 = fmaf(p[d], wpA[d][2 * h], f0);
          f1 = fmaf(p[d], wpA[d][2 * h + 1], f1);
        }
        f0 = fmaxf(f0, 0.f); f1 = fmaxf(f1, 0.f);
        asm("v_cvt_pk_bf16_f32 %0, %1, %2" : "=v"(a0.u[h]) : "v"(f0), "v"(f1));
        f0 = bf2f((unsigned short)y1[2 * h]);
        f1 = bf2f((unsigned short)y1[2 * h + 1]);
#pragma unroll
        for (int d = 0; d < 3; ++d) {
          f0 = fmaf(p[d], wpB[d][2 * h], f0);
          f1 = fmaf(p[d], wpB[d][2 * h + 1], f1);
        }
        f0 = fmaxf(f0, 0.f); f1 = fmaxf(f1, 0.f);
        asm("v_cvt_pk_bf16_f32 %0, %1, %2" : "=v"(a1.u[h]) : "v"(f0), "v"(f1));
      }
      fx4 acc[4];
#pragma unroll
      for (int t = 0; t < 4; ++t) {
        acc[t][0] = bias[t]; acc[t][1] = bias[t];
        acc[t][2] = bias[t]; acc[t][3] = bias[t];
      }
#pragma unroll
      for (int t = 0; t < 4; ++t) {
        acc[t] = __builtin_amdgcn_mfma_f32_16x16x32_bf16(a0.v, bF[t][0], acc[t], 0, 0, 0);
        acc[t] = __builtin_amdgcn_mfma_f32_16x16x32_bf16(a1.v, bF[t][1], acc[t], 0, 0, 0);
      }
      if (lg == 0) ldd[wv][l15] = dstv;
#pragma unroll
      for (int t = 0; t < 4; ++t) {
        const int col = l15 + 16 * t;
#pragma unroll
        for (int j = 0; j < 4; ++j) {
          const float v = fmaxf(acc[t][j], 0.f);
          ssum[t] += v;
          ssq[t] = fmaf(v, v, ssq[t]);
          ld2[wv][lg * 4 + j][col] = v;
        }
      }
    }
    __syncthreads();
    if (act) {
      // lane = channel; dst-sorted rows -> run-segmented max, ~2 atomics/run
      int cur = ldd[wv][0];
      float m = ld2[wv][0][lane];
#pragma unroll
      for (int r = 1; r < 16; ++r) {
        const int d = ldd[wv][r];
        const float v = ld2[wv][r][lane];
        if (d == cur) {
          m = fmaxf(m, v);
        } else {
          if (m > 0.f) atomicMax(&agg[(size_t)cur * 64 + lane], __float_as_uint(m));
          cur = d; m = v;
        }
      }
      if (m > 0.f) atomicMax(&agg[(size_t)cur * 64 + lane], __float_as_uint(m));
    }
    __syncthreads();
  }
#pragma unroll
  for (int t = 0; t < 4; ++t) {
    ssum[t] += __shfl_xor(ssum[t], 16); ssum[t] += __shfl_xor(ssum[t], 32);
    ssq[t]  += __shfl_xor(ssq[t], 16);  ssq[t]  += __shfl_xor(ssq[t], 32);
  }
  __shared__ float sred[2][64];
  if (tid < 128) ((float*)sred)[tid] = 0.f;
  __syncthreads();
  if (lg == 0) {
#pragma unroll
    for (int t = 0; t < 4; ++t) {
      atomicAdd(&sred[0][l15 + 16 * t], ssum[t]);
      atomicAdd(&sred[1][l15 + 16 * t], ssq[t]);
    }
  }
  __syncthreads();
  if (tid < 64) {
    atomicAdd((unsigned long long*)&stats[128 + tid],
              (unsigned long long)(long long)((double)sred[0][tid] * SCALE));
    atomicAdd((unsigned long long*)&stats[192 + tid],
              (unsigned long long)(long long)((double)sred[1][tid] * SCALE));
  }
}

// ---- decode max, apply BN2 affine, zero empty nodes (hist==0), stats ----
__global__ __launch_bounds__(256) void k_aggfix(
    unsigned int* __restrict__ agg, const unsigned int* __restrict__ hist,
    const float* __restrict__ coef, long long* __restrict__ stats, int total) {
  const int tid = threadIdx.x;
  const int c = tid & 63;
  const float a2 = coef[128 + c], c2 = coef[192 + c];
  __shared__ float red[256];
  float ssum = 0.f, ssq = 0.f;
  const int step = gridDim.x * 256;
  for (int i = blockIdx.x * 256 + tid; i < total; i += step) {
    const unsigned int u = agg[i];
    const unsigned int tch = hist[i >> 6];
    const float v = tch ? fmaf(a2, __uint_as_float(u), c2) : 0.f;
    ((float*)agg)[i] = v;
    ssum += v;
    ssq = fmaf(v, v, ssq);
  }
  stat_reduce(ssum, red, stats + 384);
  stat_reduce(ssq, red, stats + 448);
}

__global__ __launch_bounds__(256) void k_final(
    const float* __restrict__ aggf, const float* __restrict__ s,
    const float* __restrict__ coef, float* __restrict__ out, int total) {
  int i = blockIdx.x * 256 + threadIdx.x;
  if (i >= total) return;
  int c = i & 63;
  float v = fmaf(coef[384 + c], aggf[i], coef[448 + c]) +
            fmaf(coef[256 + c], s[i], coef[320 + c]);
  out[i] = fmaxf(v, 0.f);
}

extern "C" void kernel_launch(void* const* d_in, const int* in_sizes, int n_in,
                              void* d_out, int out_size, void* d_ws, size_t ws_size,
                              hipStream_t stream) {
  const float* x   = (const float*)d_in[0];
  const float* pos = (const float*)d_in[1];
  const int*   ei  = (const int*)d_in[2];
  const float* W1  = (const float*)d_in[3];
  const float* b1  = (const float*)d_in[4];
  const float* g1  = (const float*)d_in[5];
  const float* be1 = (const float*)d_in[6];
  const float* W2  = (const float*)d_in[7];
  const float* b2  = (const float*)d_in[8];
  const float* g2  = (const float*)d_in[9];
  const float* be2 = (const float*)d_in[10];
  const float* Ws  = (const float*)d_in[11];
  const float* bs  = (const float*)d_in[12];
  const float* gs  = (const float*)d_in[13];
  const float* bes = (const float*)d_in[14];
  const float* gf  = (const float*)d_in[15];
  const float* bef = (const float*)d_in[16];
  const int N = in_sizes[0] / CIN;   // 50000
  const int E = in_sizes[2] / 2;     // 800000

  char* ws = (char*)d_ws;
  // layout (bytes):
  const size_t o_stats = 0;                       // 4 KB
  const size_t o_hist  = 4096;                    // N*4 (pad 204800)
  const size_t o_agg   = o_hist + 204800;         // N*256
  const size_t zeroEnd = o_agg + (size_t)N * 256; // memset [0, zeroEnd)
  const size_t o_curs  = zeroEnd;                 // N*4 (pad 204800)
  const size_t o_coef  = o_curs + 204800;         // 576 floats (pad 4096)
  const size_t o_W2p   = o_coef + 4096;           // 8 KB
  const size_t o_perm  = o_W2p + 8192;            // E*4
  const size_t o_sbuf  = o_perm + (size_t)E * 4;  // N*256
  const size_t o_ybuf  = o_sbuf + (size_t)N * 256; // N*128

  long long* stats      = (long long*)(ws + o_stats);
  unsigned int* hist    = (unsigned int*)(ws + o_hist);
  unsigned int* agg     = (unsigned int*)(ws + o_agg);
  unsigned int* cursor  = (unsigned int*)(ws + o_curs);
  float* coef           = (float*)(ws + o_coef);
  float* b2p            = coef + 512;
  unsigned short* W2p   = (unsigned short*)(ws + o_W2p);
  unsigned int* perm    = (unsigned int*)(ws + o_perm);
  float* sbuf           = (float*)(ws + o_sbuf);
  unsigned short* ybuf  = (unsigned short*)(ws + o_ybuf);

  const double invE = 1.0 / (SCALE * (double)E);
  const double invN = 1.0 / (SCALE * (double)N);
  const int total = N * 64;

  hipMemsetAsync(d_ws, 0, zeroEnd, stream);

  hipLaunchKernelGGL(k_y, dim3(1024), dim3(256), 0, stream, x, W1, b1, ybuf, N);
  hipLaunchKernelGGL(k_hist, dim3(512), dim3(256), 0, stream, ei, hist, E);
  hipLaunchKernelGGL(k_scan, dim3(1), dim3(1024), 0, stream, hist, cursor, N);
  hipLaunchKernelGGL(k_short, dim3(1024), dim3(256), 0, stream, x, Ws, bs, sbuf, stats, N);
  hipLaunchKernelGGL(k_edge1, dim3(2048), dim3(256), 0, stream,
                     ei, pos, ybuf, W1, cursor, perm, stats, E);
  hipLaunchKernelGGL(k_coef, dim3(1), dim3(64), 0, stream,
                     stats + 0, stats + 64, g1, be1, coef + 0, coef + 64, invE);
  hipLaunchKernelGGL(k_coefW2, dim3(1), dim3(64), 0, stream, W2, b2, coef, W2p, b2p);
  hipLaunchKernelGGL(k_edge2, dim3(2048), dim3(256), 0, stream,
                     ybuf, ei, perm, pos, W1, W2p, b2p, stats, agg, E);
  hipLaunchKernelGGL(k_coef, dim3(1), dim3(64), 0, stream,
                     stats + 128, stats + 192, g2, be2, coef + 128, coef + 192, invE);
  hipLaunchKernelGGL(k_coef, dim3(1), dim3(64), 0, stream,
                     stats + 256, stats + 320, gs, bes, coef + 256, coef + 320, invN);
  hipLaunchKernelGGL(k_aggfix, dim3(2048), dim3(256), 0, stream,
                     agg, hist, coef, stats, total);
  hipLaunchKernelGGL(k_coef, dim3(1), dim3(64), 0, stream,
                     stats + 384, stats + 448, gf, bef, coef + 384, coef + 448, invN);
  hipLaunchKernelGGL(k_final, dim3((total + 255) / 256), dim3(256), 0, stream,
                     (const float*)agg, sbuf, coef, (float*)d_out, total);
}

// Round 4
// 461.468 us; speedup vs baseline: 1.0951x; 1.0951x over previous
//
#include <hip/hip_runtime.h>

#define CIN 61
constexpr float EPS = 1e-5f;
constexpr double SCALE = 16777216.0;  // 2^24 fixed-point deterministic stat sums

using s16x8 = __attribute__((ext_vector_type(8))) short;
using fx4   = __attribute__((ext_vector_type(4))) float;

static __device__ __forceinline__ unsigned short f2bf(float f) {
  unsigned int u = __float_as_uint(f);
  u = (u + 0x7fffu + ((u >> 16) & 1u)) >> 16;
  return (unsigned short)u;
}
static __device__ __forceinline__ float bf2f(unsigned short h) {
  return __uint_as_float(((unsigned int)h) << 16);
}

__device__ __forceinline__ void stat_reduce(float val, float* red, long long* dst_ll) {
  int tid = threadIdx.x;
  red[tid] = val;
  __syncthreads();
  if (tid < 64) {
    float t = red[tid] + red[tid + 64] + red[tid + 128] + red[tid + 192];
    atomicAdd((unsigned long long*)&dst_ll[tid],
              (unsigned long long)(long long)((double)t * SCALE));
  }
  __syncthreads();
}

// ---- node GEMV: y = bf16(x @ W1[:61] + b1) ----
__global__ __launch_bounds__(256) void k_y(
    const float* __restrict__ x, const float* __restrict__ W1,
    const float* __restrict__ b1, unsigned short* __restrict__ y, int N) {
  const int tid = threadIdx.x, lane = tid & 63, wv = tid >> 6;
  float w[64];
#pragma unroll
  for (int k = 0; k < 64; ++k) w[k] = (k < CIN) ? W1[k * 64 + lane] : 0.f;
  const float bv = b1[lane];
  __shared__ float lrow[4][64];
  const int nq = N >> 2;
  for (int q = blockIdx.x; q < nq; q += gridDim.x) {
    const int n = (q << 2) + wv;
    lrow[wv][lane] = (lane < CIN) ? x[n * CIN + lane] : 0.f;
    __syncthreads();
    float a0 = bv, a1 = 0.f, a2 = 0.f, a3 = 0.f;
    const float4* rr = (const float4*)&lrow[wv][0];
#pragma unroll
    for (int k4 = 0; k4 < 16; ++k4) {
      float4 v = rr[k4];
      a0 = fmaf(v.x, w[4 * k4 + 0], a0);
      a1 = fmaf(v.y, w[4 * k4 + 1], a1);
      a2 = fmaf(v.z, w[4 * k4 + 2], a2);
      a3 = fmaf(v.w, w[4 * k4 + 3], a3);
    }
    y[(size_t)n * 64 + lane] = f2bf((a0 + a1) + (a2 + a3));
    __syncthreads();
  }
}

// ---- shortcut GEMV: s = x @ Ws + bs (f32) + stats over N ----
__global__ __launch_bounds__(256) void k_short(
    const float* __restrict__ x, const float* __restrict__ Ws,
    const float* __restrict__ bs, float* __restrict__ s_out,
    long long* __restrict__ stats, int N) {
  const int tid = threadIdx.x, lane = tid & 63, wv = tid >> 6;
  float w[64];
#pragma unroll
  for (int k = 0; k < 64; ++k) w[k] = (k < CIN) ? Ws[k * 64 + lane] : 0.f;
  const float bv = bs[lane];
  __shared__ float lrow[4][64];
  __shared__ float red[256];
  float ssum = 0.f, ssq = 0.f;
  const int nq = N >> 2;
  for (int q = blockIdx.x; q < nq; q += gridDim.x) {
    const int n = (q << 2) + wv;
    lrow[wv][lane] = (lane < CIN) ? x[n * CIN + lane] : 0.f;
    __syncthreads();
    float a0 = bv, a1 = 0.f, a2 = 0.f, a3 = 0.f;
    const float4* rr = (const float4*)&lrow[wv][0];
#pragma unroll
    for (int k4 = 0; k4 < 16; ++k4) {
      float4 v = rr[k4];
      a0 = fmaf(v.x, w[4 * k4 + 0], a0);
      a1 = fmaf(v.y, w[4 * k4 + 1], a1);
      a2 = fmaf(v.z, w[4 * k4 + 2], a2);
      a3 = fmaf(v.w, w[4 * k4 + 3], a3);
    }
    const float acc = (a0 + a1) + (a2 + a3);
    s_out[(size_t)n * 64 + lane] = acc;
    ssum += acc;
    ssq = fmaf(acc, acc, ssq);
    __syncthreads();
  }
  stat_reduce(ssum, red, stats + 256);
  stat_reduce(ssq, red, stats + 320);
}

// ---- histogram of dst ----
__global__ __launch_bounds__(256) void k_hist(
    const int* __restrict__ ei, unsigned int* __restrict__ hist, int E) {
  int i = blockIdx.x * 256 + threadIdx.x;
  const int st = gridDim.x * 256;
  for (; i < E; i += st) atomicAdd(&hist[ei[E + i]], 1u);
}

// ---- single-block exclusive scan of hist -> cursor ----
__global__ __launch_bounds__(1024) void k_scan(
    const unsigned int* __restrict__ hist, unsigned int* __restrict__ cursor, int n) {
  const int tid = threadIdx.x;
  const int per = (n + 1023) / 1024;
  const int lo = tid * per;
  const int hi = (lo + per < n) ? lo + per : n;
  unsigned int tot = 0;
  for (int i = lo; i < hi; ++i) tot += hist[i];
  const int lane = tid & 63, w = tid >> 6;
  unsigned int incl = tot;
#pragma unroll
  for (int off = 1; off < 64; off <<= 1) {
    unsigned int t = __shfl_up(incl, off);
    if (lane >= off) incl += t;
  }
  __shared__ unsigned int wsum[16];
  if (lane == 63) wsum[w] = incl;
  __syncthreads();
  unsigned int wbase = 0;
#pragma unroll
  for (int k = 0; k < 16; ++k) wbase += (k < w) ? wsum[k] : 0u;
  unsigned int run = wbase + incl - tot;  // exclusive prefix at lo
  for (int i = lo; i < hi; ++i) {
    unsigned int h = hist[i];
    cursor[i] = run;
    run += h;
  }
}

// ---- thread-per-edge counting-sort scatter (high TLP hides atomic latency) ----
__global__ __launch_bounds__(256) void k_scatter(
    const int* __restrict__ ei, unsigned int* __restrict__ cursor,
    unsigned int* __restrict__ perm, int E) {
  int i = blockIdx.x * 256 + threadIdx.x;
  const int st = gridDim.x * 256;
  for (; i < E; i += st) {
    const int dst = ei[E + i];
    const unsigned int off = atomicAdd(&cursor[dst], 1u);
    perm[off] = (unsigned int)i;
  }
}

// ---- edge pass 1 (stats only): 4 edges/wave, 16 lanes x ushort4 per y-row ----
__global__ __launch_bounds__(256) void k_edge1(
    const int* __restrict__ ei, const float* __restrict__ pos,
    const unsigned short* __restrict__ y, const float* __restrict__ W1,
    long long* __restrict__ stats, int E) {
  const int tid = threadIdx.x, lane = tid & 63, wv = tid >> 6;
  const int g = lane >> 4, c16 = lane & 15;
  float wp[3][4];
#pragma unroll
  for (int d = 0; d < 3; ++d)
#pragma unroll
    for (int i = 0; i < 4; ++i) wp[d][i] = W1[(61 + d) * 64 + 4 * c16 + i];
  float ssum[4] = {0.f, 0.f, 0.f, 0.f}, ssq[4] = {0.f, 0.f, 0.f, 0.f};
  const int ngrp = E >> 2;  // groups of 4 edges (E % 4 == 0)
  const int nw = gridDim.x * 4;
  for (int q = blockIdx.x * 4 + wv; q < ngrp; q += nw) {
    const int e = (q << 2) + g;
    const int src = ei[e], dst = ei[E + e];
    float pv = 0.f;
    if (c16 < 3) pv = pos[src * 3 + c16] - pos[dst * 3 + c16];
    const ushort4 yv = *(const ushort4*)(y + (size_t)src * 64 + 4 * c16);
    const float p0 = __shfl(pv, g * 16 + 0);
    const float p1 = __shfl(pv, g * 16 + 1);
    const float p2 = __shfl(pv, g * 16 + 2);
    const unsigned short* yc = (const unsigned short*)&yv;
#pragma unroll
    for (int i = 0; i < 4; ++i) {
      float t = bf2f(yc[i]);
      t = fmaf(p0, wp[0][i], t);
      t = fmaf(p1, wp[1][i], t);
      t = fmaf(p2, wp[2][i], t);
      t = fmaxf(t, 0.f);
      ssum[i] += t;
      ssq[i] = fmaf(t, t, ssq[i]);
    }
  }
#pragma unroll
  for (int i = 0; i < 4; ++i) {
    ssum[i] += __shfl_xor(ssum[i], 16); ssum[i] += __shfl_xor(ssum[i], 32);
    ssq[i]  += __shfl_xor(ssq[i], 16);  ssq[i]  += __shfl_xor(ssq[i], 32);
  }
  __shared__ float sred[2][64];
  if (tid < 128) ((float*)sred)[tid] = 0.f;
  __syncthreads();
  if (g == 0) {
#pragma unroll
    for (int i = 0; i < 4; ++i) {
      atomicAdd(&sred[0][4 * c16 + i], ssum[i]);
      atomicAdd(&sred[1][4 * c16 + i], ssq[i]);
    }
  }
  __syncthreads();
  if (tid < 64) {
    atomicAdd((unsigned long long*)&stats[0 + tid],
              (unsigned long long)(long long)((double)sred[0][tid] * SCALE));
    atomicAdd((unsigned long long*)&stats[64 + tid],
              (unsigned long long)(long long)((double)sred[1][tid] * SCALE));
  }
}

// ---- BN coef: a = g*rsqrt(var+eps), c = be - mean*a ----
__global__ void k_coef(const long long* __restrict__ sum,
                       const long long* __restrict__ sq,
                       const float* __restrict__ g, const float* __restrict__ be,
                       float* __restrict__ a_out, float* __restrict__ c_out,
                       double inv) {
  int c = threadIdx.x;
  double m = (double)sum[c] * inv;
  double v = (double)sq[c] * inv - m * m;
  float rs = rsqrtf((float)v + EPS);
  float a = g[c] * rs;
  a_out[c] = a;
  c_out[c] = fmaf(-(float)m, a, be[c]);
}

// ---- fold BN1 affine into W2 ----
__global__ void k_coefW2(const float* __restrict__ W2, const float* __restrict__ b2,
                         const float* __restrict__ coef, unsigned short* __restrict__ W2p,
                         float* __restrict__ b2p) {
  const int c = threadIdx.x;
  float acc = b2[c];
  for (int k = 0; k < 64; ++k) {
    const float w = W2[k * 64 + c];
    acc = fmaf(coef[64 + k], w, acc);
    W2p[k * 64 + c] = f2bf(coef[k] * w);
  }
  b2p[c] = acc;
}

// ---- edge pass 2 (fused, dst-sorted): recompute t1 in frag layout, MFMA,
//      stats, run-segmented scatter-max ----
__global__ __launch_bounds__(256) void k_edge2(
    const unsigned short* __restrict__ y, const int* __restrict__ ei,
    const unsigned int* __restrict__ perm, const float* __restrict__ pos,
    const float* __restrict__ W1, const unsigned short* __restrict__ W2p,
    const float* __restrict__ b2p, long long* __restrict__ stats,
    unsigned int* __restrict__ agg, int E) {
  const int tid = threadIdx.x, lane = tid & 63, wv = tid >> 6;
  const int l15 = lane & 15, lg = lane >> 4;
  s16x8 bF[4][2];
#pragma unroll
  for (int t = 0; t < 4; ++t) {
    const int col = l15 + 16 * t;
#pragma unroll
    for (int s = 0; s < 2; ++s)
#pragma unroll
      for (int i = 0; i < 8; ++i)
        bF[t][s][i] = (short)W2p[(s * 32 + lg * 8 + i) * 64 + col];
  }
  float bias[4];
#pragma unroll
  for (int t = 0; t < 4; ++t) bias[t] = b2p[l15 + 16 * t];
  float wpA[3][8], wpB[3][8];
#pragma unroll
  for (int d = 0; d < 3; ++d)
#pragma unroll
    for (int i = 0; i < 8; ++i) {
      wpA[d][i] = W1[(61 + d) * 64 + lg * 8 + i];
      wpB[d][i] = W1[(61 + d) * 64 + 32 + lg * 8 + i];
    }
  __shared__ float ld2[4][16][64];
  __shared__ int ldd[4][16];
  float ssum[4] = {0.f, 0.f, 0.f, 0.f}, ssq[4] = {0.f, 0.f, 0.f, 0.f};
  const int ntile = E >> 4;
  const int tps = gridDim.x * 4;
  const int nsteps = (ntile + tps - 1) / tps;
  for (int s = 0; s < nsteps; ++s) {
    const int tile = s * tps + blockIdx.x * 4 + wv;
    const bool act = tile < ntile;
    if (act) {
      const int rbase = tile << 4;
      const int eid = (int)perm[rbase + l15];
      const int src = ei[eid];
      const int dstv = ei[E + eid];
      float p[3];
#pragma unroll
      for (int d = 0; d < 3; ++d) p[d] = pos[src * 3 + d] - pos[dstv * 3 + d];
      const unsigned short* yr = y + (size_t)src * 64 + lg * 8;
      const s16x8 y0 = *(const s16x8*)yr;
      const s16x8 y1 = *(const s16x8*)(yr + 32);
      union { s16x8 v; unsigned int u[4]; } a0, a1;
#pragma unroll
      for (int h = 0; h < 4; ++h) {
        float f0 = bf2f((unsigned short)y0[2 * h]);
        float f1 = bf2f((unsigned short)y0[2 * h + 1]);
#pragma unroll
        for (int d = 0; d < 3; ++d) {
          f0 = fmaf(p[d], wpA[d][2 * h], f0);
          f1 = fmaf(p[d], wpA[d][2 * h + 1], f1);
        }
        f0 = fmaxf(f0, 0.f); f1 = fmaxf(f1, 0.f);
        asm("v_cvt_pk_bf16_f32 %0, %1, %2" : "=v"(a0.u[h]) : "v"(f0), "v"(f1));
        f0 = bf2f((unsigned short)y1[2 * h]);
        f1 = bf2f((unsigned short)y1[2 * h + 1]);
#pragma unroll
        for (int d = 0; d < 3; ++d) {
          f0 = fmaf(p[d], wpB[d][2 * h], f0);
          f1 = fmaf(p[d], wpB[d][2 * h + 1], f1);
        }
        f0 = fmaxf(f0, 0.f); f1 = fmaxf(f1, 0.f);
        asm("v_cvt_pk_bf16_f32 %0, %1, %2" : "=v"(a1.u[h]) : "v"(f0), "v"(f1));
      }
      fx4 acc[4];
#pragma unroll
      for (int t = 0; t < 4; ++t) {
        acc[t][0] = bias[t]; acc[t][1] = bias[t];
        acc[t][2] = bias[t]; acc[t][3] = bias[t];
      }
#pragma unroll
      for (int t = 0; t < 4; ++t) {
        acc[t] = __builtin_amdgcn_mfma_f32_16x16x32_bf16(a0.v, bF[t][0], acc[t], 0, 0, 0);
        acc[t] = __builtin_amdgcn_mfma_f32_16x16x32_bf16(a1.v, bF[t][1], acc[t], 0, 0, 0);
      }
      if (lg == 0) ldd[wv][l15] = dstv;
#pragma unroll
      for (int t = 0; t < 4; ++t) {
        const int col = l15 + 16 * t;
#pragma unroll
        for (int j = 0; j < 4; ++j) {
          const float v = fmaxf(acc[t][j], 0.f);
          ssum[t] += v;
          ssq[t] = fmaf(v, v, ssq[t]);
          ld2[wv][lg * 4 + j][col] = v;
        }
      }
    }
    __syncthreads();
    if (act) {
      int cur = ldd[wv][0];
      float m = ld2[wv][0][lane];
#pragma unroll
      for (int r = 1; r < 16; ++r) {
        const int d = ldd[wv][r];
        const float v = ld2[wv][r][lane];
        if (d == cur) {
          m = fmaxf(m, v);
        } else {
          if (m > 0.f) atomicMax(&agg[(size_t)cur * 64 + lane], __float_as_uint(m));
          cur = d; m = v;
        }
      }
      if (m > 0.f) atomicMax(&agg[(size_t)cur * 64 + lane], __float_as_uint(m));
    }
    __syncthreads();
  }
#pragma unroll
  for (int t = 0; t < 4; ++t) {
    ssum[t] += __shfl_xor(ssum[t], 16); ssum[t] += __shfl_xor(ssum[t], 32);
    ssq[t]  += __shfl_xor(ssq[t], 16);  ssq[t]  += __shfl_xor(ssq[t], 32);
  }
  __shared__ float sred[2][64];
  if (tid < 128) ((float*)sred)[tid] = 0.f;
  __syncthreads();
  if (lg == 0) {
#pragma unroll
    for (int t = 0; t < 4; ++t) {
      atomicAdd(&sred[0][l15 + 16 * t], ssum[t]);
      atomicAdd(&sred[1][l15 + 16 * t], ssq[t]);
    }
  }
  __syncthreads();
  if (tid < 64) {
    atomicAdd((unsigned long long*)&stats[128 + tid],
              (unsigned long long)(long long)((double)sred[0][tid] * SCALE));
    atomicAdd((unsigned long long*)&stats[192 + tid],
              (unsigned long long)(long long)((double)sred[1][tid] * SCALE));
  }
}

// ---- decode max, apply BN2 affine, zero empty nodes (hist==0), stats ----
__global__ __launch_bounds__(256) void k_aggfix(
    unsigned int* __restrict__ agg, const unsigned int* __restrict__ hist,
    const float* __restrict__ coef, long long* __restrict__ stats, int total) {
  const int tid = threadIdx.x;
  const int c = tid & 63;
  const float a2 = coef[128 + c], c2 = coef[192 + c];
  __shared__ float red[256];
  float ssum = 0.f, ssq = 0.f;
  const int step = gridDim.x * 256;
  for (int i = blockIdx.x * 256 + tid; i < total; i += step) {
    const unsigned int u = agg[i];
    const unsigned int tch = hist[i >> 6];
    const float v = tch ? fmaf(a2, __uint_as_float(u), c2) : 0.f;
    ((float*)agg)[i] = v;
    ssum += v;
    ssq = fmaf(v, v, ssq);
  }
  stat_reduce(ssum, red, stats + 384);
  stat_reduce(ssq, red, stats + 448);
}

__global__ __launch_bounds__(256) void k_final(
    const float* __restrict__ aggf, const float* __restrict__ s,
    const float* __restrict__ coef, float* __restrict__ out, int total) {
  int i = blockIdx.x * 256 + threadIdx.x;
  if (i >= total) return;
  int c = i & 63;
  float v = fmaf(coef[384 + c], aggf[i], coef[448 + c]) +
            fmaf(coef[256 + c], s[i], coef[320 + c]);
  out[i] = fmaxf(v, 0.f);
}

extern "C" void kernel_launch(void* const* d_in, const int* in_sizes, int n_in,
                              void* d_out, int out_size, void* d_ws, size_t ws_size,
                              hipStream_t stream) {
  const float* x   = (const float*)d_in[0];
  const float* pos = (const float*)d_in[1];
  const int*   ei  = (const int*)d_in[2];
  const float* W1  = (const float*)d_in[3];
  const float* b1  = (const float*)d_in[4];
  const float* g1  = (const float*)d_in[5];
  const float* be1 = (const float*)d_in[6];
  const float* W2  = (const float*)d_in[7];
  const float* b2  = (const float*)d_in[8];
  const float* g2  = (const float*)d_in[9];
  const float* be2 = (const float*)d_in[10];
  const float* Ws  = (const float*)d_in[11];
  const float* bs  = (const float*)d_in[12];
  const float* gs  = (const float*)d_in[13];
  const float* bes = (const float*)d_in[14];
  const float* gf  = (const float*)d_in[15];
  const float* bef = (const float*)d_in[16];
  const int N = in_sizes[0] / CIN;   // 50000
  const int E = in_sizes[2] / 2;     // 800000

  char* ws = (char*)d_ws;
  const size_t o_stats = 0;                       // 4 KB
  const size_t o_hist  = 4096;                    // N*4 (pad 204800)
  const size_t o_agg   = o_hist + 204800;         // N*256
  const size_t zeroEnd = o_agg + (size_t)N * 256; // memset [0, zeroEnd)
  const size_t o_curs  = zeroEnd;                 // N*4 (pad 204800)
  const size_t o_coef  = o_curs + 204800;         // 576 floats (pad 4096)
  const size_t o_W2p   = o_coef + 4096;           // 8 KB
  const size_t o_perm  = o_W2p + 8192;            // E*4
  const size_t o_sbuf  = o_perm + (size_t)E * 4;  // N*256
  const size_t o_ybuf  = o_sbuf + (size_t)N * 256; // N*128

  long long* stats      = (long long*)(ws + o_stats);
  unsigned int* hist    = (unsigned int*)(ws + o_hist);
  unsigned int* agg     = (unsigned int*)(ws + o_agg);
  unsigned int* cursor  = (unsigned int*)(ws + o_curs);
  float* coef           = (float*)(ws + o_coef);
  float* b2p            = coef + 512;
  unsigned short* W2p   = (unsigned short*)(ws + o_W2p);
  unsigned int* perm    = (unsigned int*)(ws + o_perm);
  float* sbuf           = (float*)(ws + o_sbuf);
  unsigned short* ybuf  = (unsigned short*)(ws + o_ybuf);

  const double invE = 1.0 / (SCALE * (double)E);
  const double invN = 1.0 / (SCALE * (double)N);
  const int total = N * 64;

  hipMemsetAsync(d_ws, 0, zeroEnd, stream);

  hipLaunchKernelGGL(k_y, dim3(1024), dim3(256), 0, stream, x, W1, b1, ybuf, N);
  hipLaunchKernelGGL(k_hist, dim3(512), dim3(256), 0, stream, ei, hist, E);
  hipLaunchKernelGGL(k_scan, dim3(1), dim3(1024), 0, stream, hist, cursor, N);
  hipLaunchKernelGGL(k_scatter, dim3(1024), dim3(256), 0, stream, ei, cursor, perm, E);
  hipLaunchKernelGGL(k_short, dim3(1024), dim3(256), 0, stream, x, Ws, bs, sbuf, stats, N);
  hipLaunchKernelGGL(k_edge1, dim3(2048), dim3(256), 0, stream,
                     ei, pos, ybuf, W1, stats, E);
  hipLaunchKernelGGL(k_coef, dim3(1), dim3(64), 0, stream,
                     stats + 0, stats + 64, g1, be1, coef + 0, coef + 64, invE);
  hipLaunchKernelGGL(k_coefW2, dim3(1), dim3(64), 0, stream, W2, b2, coef, W2p, b2p);
  hipLaunchKernelGGL(k_edge2, dim3(2048), dim3(256), 0, stream,
                     ybuf, ei, perm, pos, W1, W2p, b2p, stats, agg, E);
  hipLaunchKernelGGL(k_coef, dim3(1), dim3(64), 0, stream,
                     stats + 128, stats + 192, g2, be2, coef + 128, coef + 192, invE);
  hipLaunchKernelGGL(k_coef, dim3(1), dim3(64), 0, stream,
                     stats + 256, stats + 320, gs, bes, coef + 256, coef + 320, invN);
  hipLaunchKernelGGL(k_aggfix, dim3(2048), dim3(256), 0, stream,
                     agg, hist, coef, stats, total);
  hipLaunchKernelGGL(k_coef, dim3(1), dim3(64), 0, stream,
                     stats + 384, stats + 448, gf, bef, coef + 384, coef + 448, invN);
  hipLaunchKernelGGL(k_final, dim3((total + 255) / 256), dim3(256), 0, stream,
                     (const float*)agg, sbuf, coef, (float*)d_out, total);
}

// Round 5
// 373.354 us; speedup vs baseline: 1.3536x; 1.2360x over previous
//
#include <hip/hip_runtime.h>

#define CIN 61
constexpr float EPS = 1e-5f;
constexpr double SCALE = 16777216.0;  // 2^24 fixed-point deterministic stat sums

using s16x8 = __attribute__((ext_vector_type(8))) short;
using fx4   = __attribute__((ext_vector_type(4))) float;

static __device__ __forceinline__ unsigned short f2bf(float f) {
  unsigned int u = __float_as_uint(f);
  u = (u + 0x7fffu + ((u >> 16) & 1u)) >> 16;
  return (unsigned short)u;
}
static __device__ __forceinline__ float bf2f(unsigned short h) {
  return __uint_as_float(((unsigned int)h) << 16);
}

__device__ __forceinline__ void stat_reduce(float val, float* red, long long* dst_ll) {
  int tid = threadIdx.x;
  red[tid] = val;
  __syncthreads();
  if (tid < 64) {
    float t = red[tid] + red[tid + 64] + red[tid + 128] + red[tid + 192];
    atomicAdd((unsigned long long*)&dst_ll[tid],
              (unsigned long long)(long long)((double)t * SCALE));
  }
  __syncthreads();
}

// ---- node GEMV: y = bf16(x @ W1[:61] + b1); fused dst histogram ----
__global__ __launch_bounds__(256) void k_y(
    const float* __restrict__ x, const float* __restrict__ W1,
    const float* __restrict__ b1, unsigned short* __restrict__ y, int N,
    const int* __restrict__ ei, unsigned int* __restrict__ hist, int E) {
  const int tid = threadIdx.x, lane = tid & 63, wv = tid >> 6;
  float w[64];
#pragma unroll
  for (int k = 0; k < 64; ++k) w[k] = (k < CIN) ? W1[k * 64 + lane] : 0.f;
  const float bv = b1[lane];
  __shared__ float lrow[4][64];
  const int nq = N >> 2;
  for (int q = blockIdx.x; q < nq; q += gridDim.x) {
    const int n = (q << 2) + wv;
    lrow[wv][lane] = (lane < CIN) ? x[n * CIN + lane] : 0.f;
    __syncthreads();
    float a0 = bv, a1 = 0.f, a2 = 0.f, a3 = 0.f;
    const float4* rr = (const float4*)&lrow[wv][0];
#pragma unroll
    for (int k4 = 0; k4 < 16; ++k4) {
      float4 v = rr[k4];
      a0 = fmaf(v.x, w[4 * k4 + 0], a0);
      a1 = fmaf(v.y, w[4 * k4 + 1], a1);
      a2 = fmaf(v.z, w[4 * k4 + 2], a2);
      a3 = fmaf(v.w, w[4 * k4 + 3], a3);
    }
    y[(size_t)n * 64 + lane] = f2bf((a0 + a1) + (a2 + a3));
    __syncthreads();
  }
  // fused histogram of dst (independent work, overlaps)
  for (int i = blockIdx.x * 256 + tid; i < E; i += gridDim.x * 256)
    atomicAdd(&hist[ei[E + i]], 1u);
}

// ---- shortcut GEMV: s = bf16(x @ Ws + bs) + f32 stats over N ----
__global__ __launch_bounds__(256) void k_short(
    const float* __restrict__ x, const float* __restrict__ Ws,
    const float* __restrict__ bs, unsigned short* __restrict__ s_out,
    long long* __restrict__ stats, int N) {
  const int tid = threadIdx.x, lane = tid & 63, wv = tid >> 6;
  float w[64];
#pragma unroll
  for (int k = 0; k < 64; ++k) w[k] = (k < CIN) ? Ws[k * 64 + lane] : 0.f;
  const float bv = bs[lane];
  __shared__ float lrow[4][64];
  __shared__ float red[256];
  float ssum = 0.f, ssq = 0.f;
  const int nq = N >> 2;
  for (int q = blockIdx.x; q < nq; q += gridDim.x) {
    const int n = (q << 2) + wv;
    lrow[wv][lane] = (lane < CIN) ? x[n * CIN + lane] : 0.f;
    __syncthreads();
    float a0 = bv, a1 = 0.f, a2 = 0.f, a3 = 0.f;
    const float4* rr = (const float4*)&lrow[wv][0];
#pragma unroll
    for (int k4 = 0; k4 < 16; ++k4) {
      float4 v = rr[k4];
      a0 = fmaf(v.x, w[4 * k4 + 0], a0);
      a1 = fmaf(v.y, w[4 * k4 + 1], a1);
      a2 = fmaf(v.z, w[4 * k4 + 2], a2);
      a3 = fmaf(v.w, w[4 * k4 + 3], a3);
    }
    const float acc = (a0 + a1) + (a2 + a3);
    s_out[(size_t)n * 64 + lane] = f2bf(acc);
    ssum += acc;
    ssq = fmaf(acc, acc, ssq);
    __syncthreads();
  }
  stat_reduce(ssum, red, stats + 256);
  stat_reduce(ssq, red, stats + 320);
}

// ---- single-block exclusive scan of hist -> cursor ----
__global__ __launch_bounds__(1024) void k_scan(
    const unsigned int* __restrict__ hist, unsigned int* __restrict__ cursor, int n) {
  const int tid = threadIdx.x;
  const int per = (n + 1023) / 1024;
  const int lo = tid * per;
  const int hi = (lo + per < n) ? lo + per : n;
  unsigned int tot = 0;
  for (int i = lo; i < hi; ++i) tot += hist[i];
  const int lane = tid & 63, w = tid >> 6;
  unsigned int incl = tot;
#pragma unroll
  for (int off = 1; off < 64; off <<= 1) {
    unsigned int t = __shfl_up(incl, off);
    if (lane >= off) incl += t;
  }
  __shared__ unsigned int wsum[16];
  if (lane == 63) wsum[w] = incl;
  __syncthreads();
  unsigned int wbase = 0;
#pragma unroll
  for (int k = 0; k < 16; ++k) wbase += (k < w) ? wsum[k] : 0u;
  unsigned int run = wbase + incl - tot;  // exclusive prefix at lo
  for (int i = lo; i < hi; ++i) {
    unsigned int h = hist[i];
    cursor[i] = run;
    run += h;
  }
}

// ---- edge pass 1 (fused): compute t1 once, stats, and store bf16 t1 row at
//      its dst-sorted slot (scattered WRITE, so edge2 streams contiguously) ----
__global__ __launch_bounds__(256) void k_edge1s(
    const int* __restrict__ ei, const float* __restrict__ pos,
    const unsigned short* __restrict__ y, const float* __restrict__ W1,
    unsigned int* __restrict__ cursor, unsigned short* __restrict__ t1S,
    unsigned short* __restrict__ dstS, long long* __restrict__ stats, int E) {
  const int tid = threadIdx.x, lane = tid & 63, wv = tid >> 6;
  const int g = lane >> 4, c16 = lane & 15;
  float wp[3][4];
#pragma unroll
  for (int d = 0; d < 3; ++d)
#pragma unroll
    for (int i = 0; i < 4; ++i) wp[d][i] = W1[(61 + d) * 64 + 4 * c16 + i];
  float ssum[4] = {0.f, 0.f, 0.f, 0.f}, ssq[4] = {0.f, 0.f, 0.f, 0.f};
  const int ngrp = E >> 2;  // E % 4 == 0
  const int nw = gridDim.x * 4;
  for (int q = blockIdx.x * 4 + wv; q < ngrp; q += nw) {
    const int e = (q << 2) + g;
    const int src = ei[e], dst = ei[E + e];
    float pv = 0.f;
    if (c16 < 3) pv = pos[src * 3 + c16] - pos[dst * 3 + c16];
    const float p0 = __shfl(pv, g * 16 + 0);
    const float p1 = __shfl(pv, g * 16 + 1);
    const float p2 = __shfl(pv, g * 16 + 2);
    const ushort4 yv = *(const ushort4*)(y + (size_t)src * 64 + 4 * c16);
    const unsigned short* yc = (const unsigned short*)&yv;
    float t[4];
#pragma unroll
    for (int i = 0; i < 4; ++i) {
      float v = bf2f(yc[i]);
      v = fmaf(p0, wp[0][i], v);
      v = fmaf(p1, wp[1][i], v);
      v = fmaf(p2, wp[2][i], v);
      v = fmaxf(v, 0.f);
      t[i] = v;
      ssum[i] += v;
      ssq[i] = fmaf(v, v, ssq[i]);
    }
    unsigned int off = 0;
    if (c16 == 0) off = atomicAdd(&cursor[dst], 1u);
    off = __shfl(off, g * 16);
    ushort4 tb;
    tb.x = f2bf(t[0]); tb.y = f2bf(t[1]); tb.z = f2bf(t[2]); tb.w = f2bf(t[3]);
    *(ushort4*)(t1S + (size_t)off * 64 + 4 * c16) = tb;
    if (c16 == 0) dstS[off] = (unsigned short)dst;
  }
#pragma unroll
  for (int i = 0; i < 4; ++i) {
    ssum[i] += __shfl_xor(ssum[i], 16); ssum[i] += __shfl_xor(ssum[i], 32);
    ssq[i]  += __shfl_xor(ssq[i], 16);  ssq[i]  += __shfl_xor(ssq[i], 32);
  }
  __shared__ float sred[2][64];
  if (tid < 128) ((float*)sred)[tid] = 0.f;
  __syncthreads();
  if (g == 0) {
#pragma unroll
    for (int i = 0; i < 4; ++i) {
      atomicAdd(&sred[0][4 * c16 + i], ssum[i]);
      atomicAdd(&sred[1][4 * c16 + i], ssq[i]);
    }
  }
  __syncthreads();
  if (tid < 64) {
    atomicAdd((unsigned long long*)&stats[0 + tid],
              (unsigned long long)(long long)((double)sred[0][tid] * SCALE));
    atomicAdd((unsigned long long*)&stats[64 + tid],
              (unsigned long long)(long long)((double)sred[1][tid] * SCALE));
  }
}

// ---- BN1 coef + fold into W2 (one tiny kernel, 64 threads) ----
__global__ void k_coefA(const long long* __restrict__ stats,
                        const float* __restrict__ g1, const float* __restrict__ be1,
                        const float* __restrict__ W2, const float* __restrict__ b2,
                        unsigned short* __restrict__ W2p, float* __restrict__ b2p,
                        double invE) {
  const int c = threadIdx.x;
  __shared__ float a1s[64], c1s[64];
  double m = (double)stats[c] * invE;
  double v = (double)stats[64 + c] * invE - m * m;
  float a = g1[c] * rsqrtf((float)v + EPS);
  a1s[c] = a;
  c1s[c] = fmaf(-(float)m, a, be1[c]);
  __syncthreads();
  float acc = b2[c];
  for (int k = 0; k < 64; ++k) {
    const float w = W2[k * 64 + c];
    acc = fmaf(c1s[k], w, acc);
    W2p[k * 64 + c] = f2bf(a1s[k] * w);
  }
  b2p[c] = acc;
}

// ---- edge pass 2: contiguous streaming MFMA + stats + run-segmented max.
//      No block barriers: per-wave LDS buffers only. ----
__global__ __launch_bounds__(256) void k_edge2(
    const unsigned short* __restrict__ t1S, const unsigned short* __restrict__ dstS,
    const unsigned short* __restrict__ W2p, const float* __restrict__ b2p,
    long long* __restrict__ stats, unsigned int* __restrict__ agg, int E) {
  const int tid = threadIdx.x, lane = tid & 63, wv = tid >> 6;
  const int l15 = lane & 15, lg = lane >> 4;
  s16x8 bF[4][2];
#pragma unroll
  for (int t = 0; t < 4; ++t) {
    const int col = l15 + 16 * t;
#pragma unroll
    for (int s = 0; s < 2; ++s)
#pragma unroll
      for (int i = 0; i < 8; ++i)
        bF[t][s][i] = (short)W2p[(s * 32 + lg * 8 + i) * 64 + col];
  }
  float bias[4];
#pragma unroll
  for (int t = 0; t < 4; ++t) bias[t] = b2p[l15 + 16 * t];
  __shared__ float ld2[4][16][68];  // pad 68: <=2-way bank aliasing (free)
  __shared__ int ldd[4][16];
  float ssum[4] = {0.f, 0.f, 0.f, 0.f}, ssq[4] = {0.f, 0.f, 0.f, 0.f};
  const int ntile = E >> 4;
  const int nw = gridDim.x * 4;
  for (int tile = blockIdx.x * 4 + wv; tile < ntile; tile += nw) {
    const int rbase = tile << 4;
    const unsigned short* arow = t1S + (size_t)(rbase + l15) * 64 + lg * 8;
    const s16x8 aF0 = *(const s16x8*)(arow);
    const s16x8 aF1 = *(const s16x8*)(arow + 32);
    if (lg == 0) ldd[wv][l15] = (int)dstS[rbase + l15];
    fx4 acc[4];
#pragma unroll
    for (int t = 0; t < 4; ++t) {
      acc[t][0] = bias[t]; acc[t][1] = bias[t];
      acc[t][2] = bias[t]; acc[t][3] = bias[t];
    }
#pragma unroll
    for (int t = 0; t < 4; ++t) {
      acc[t] = __builtin_amdgcn_mfma_f32_16x16x32_bf16(aF0, bF[t][0], acc[t], 0, 0, 0);
      acc[t] = __builtin_amdgcn_mfma_f32_16x16x32_bf16(aF1, bF[t][1], acc[t], 0, 0, 0);
    }
#pragma unroll
    for (int t = 0; t < 4; ++t) {
      const int col = l15 + 16 * t;
#pragma unroll
      for (int j = 0; j < 4; ++j) {
        const float v = fmaxf(acc[t][j], 0.f);
        ssum[t] += v;
        ssq[t] = fmaf(v, v, ssq[t]);
        ld2[wv][lg * 4 + j][col] = v;
      }
    }
    __builtin_amdgcn_wave_barrier();  // intra-wave: order LDS writes before reads
    {
      int cur = ldd[wv][0];
      float m = ld2[wv][0][lane];
#pragma unroll
      for (int r = 1; r < 16; ++r) {
        const int d = ldd[wv][r];
        const float v = ld2[wv][r][lane];
        if (d == cur) {
          m = fmaxf(m, v);
        } else {
          atomicMax(&agg[(size_t)cur * 64 + lane], __float_as_uint(m) | 0x80000000u);
          cur = d; m = v;
        }
      }
      atomicMax(&agg[(size_t)cur * 64 + lane], __float_as_uint(m) | 0x80000000u);
    }
    __builtin_amdgcn_wave_barrier();  // order reads before next tile's writes
  }
#pragma unroll
  for (int t = 0; t < 4; ++t) {
    ssum[t] += __shfl_xor(ssum[t], 16); ssum[t] += __shfl_xor(ssum[t], 32);
    ssq[t]  += __shfl_xor(ssq[t], 16);  ssq[t]  += __shfl_xor(ssq[t], 32);
  }
  __shared__ float sred[2][64];
  if (tid < 128) ((float*)sred)[tid] = 0.f;
  __syncthreads();
  if (lg == 0) {
#pragma unroll
    for (int t = 0; t < 4; ++t) {
      atomicAdd(&sred[0][l15 + 16 * t], ssum[t]);
      atomicAdd(&sred[1][l15 + 16 * t], ssq[t]);
    }
  }
  __syncthreads();
  if (tid < 64) {
    atomicAdd((unsigned long long*)&stats[128 + tid],
              (unsigned long long)(long long)((double)sred[0][tid] * SCALE));
    atomicAdd((unsigned long long*)&stats[192 + tid],
              (unsigned long long)(long long)((double)sred[1][tid] * SCALE));
  }
}

// ---- stats of raw maxima over nonempty nodes + nonempty count (flag bit) ----
__global__ __launch_bounds__(256) void k_aggfix(
    const unsigned int* __restrict__ agg, long long* __restrict__ stats, int total) {
  const int tid = threadIdx.x;
  __shared__ float red[256];
  float ssum = 0.f, ssq = 0.f, kcf = 0.f;
  const int step = gridDim.x * 256;
  for (int i = blockIdx.x * 256 + tid; i < total; i += step) {
    const unsigned int u = agg[i];
    if (u >> 31) {
      const float v = __uint_as_float(u & 0x7fffffffu);
      ssum += v;
      ssq = fmaf(v, v, ssq);
      if ((i & 63) == 0) kcf += 1.f;
    }
  }
  stat_reduce(ssum, red, stats + 384);
  stat_reduce(ssq, red, stats + 448);
  stat_reduce(kcf, red, stats + 512);
}

// ---- all remaining BN coefs, composed for the final pass (64 threads) ----
// coef: [0)=Aagg, [64)=Cagg, [128)=CE(empty), [192)=aS, [256)=cS
__global__ void k_coefB(const long long* __restrict__ stats,
                        const float* __restrict__ g2, const float* __restrict__ be2,
                        const float* __restrict__ gs, const float* __restrict__ bes,
                        const float* __restrict__ gf, const float* __restrict__ bef,
                        float* __restrict__ coef, double invE, double invN, int N) {
  const int c = threadIdx.x;
  // BN2 (over E edges)
  double m2 = (double)stats[128 + c] * invE;
  double v2 = (double)stats[192 + c] * invE - m2 * m2;
  float a2 = g2[c] * rsqrtf((float)v2 + EPS);
  float c2 = fmaf(-(float)m2, a2, be2[c]);
  // BNs (over N nodes)
  double mS = (double)stats[256 + c] * invN;
  double vS = (double)stats[320 + c] * invN - mS * mS;
  float aS = gs[c] * rsqrtf((float)vS + EPS);
  float cS = fmaf(-(float)mS, aS, bes[c]);
  // BNf over v = nonempty ? a2*u+c2 : 0, composed from u-stats
  double su = (double)stats[384 + c] / SCALE;
  double qu = (double)stats[448 + c] / SCALE;
  double K  = (double)stats[512] / SCALE;
  double sv = (double)a2 * su + (double)c2 * K;
  double qv = (double)a2 * a2 * qu + 2.0 * a2 * c2 * su + (double)c2 * c2 * K;
  double mv = sv / N;
  double vv = qv / N - mv * mv;
  float aF = gf[c] * rsqrtf((float)vv + EPS);
  float cF = fmaf(-(float)mv, aF, bef[c]);
  coef[c]       = aF * a2;
  coef[64 + c]  = fmaf(aF, c2, cF);
  coef[128 + c] = cF;
  coef[192 + c] = aS;
  coef[256 + c] = cS;
}

__global__ __launch_bounds__(256) void k_final(
    const unsigned int* __restrict__ agg, const unsigned short* __restrict__ sbuf,
    const float* __restrict__ coef, float* __restrict__ out, int total) {
  int i = blockIdx.x * 256 + threadIdx.x;
  if (i >= total) return;
  const int c = i & 63;
  const unsigned int u = agg[i];
  float base;
  if (u >> 31)
    base = fmaf(coef[c], __uint_as_float(u & 0x7fffffffu), coef[64 + c]);
  else
    base = coef[128 + c];
  const float sv = fmaf(coef[192 + c], bf2f(sbuf[i]), coef[256 + c]);
  out[i] = fmaxf(base + sv, 0.f);
}

extern "C" void kernel_launch(void* const* d_in, const int* in_sizes, int n_in,
                              void* d_out, int out_size, void* d_ws, size_t ws_size,
                              hipStream_t stream) {
  const float* x   = (const float*)d_in[0];
  const float* pos = (const float*)d_in[1];
  const int*   ei  = (const int*)d_in[2];
  const float* W1  = (const float*)d_in[3];
  const float* b1  = (const float*)d_in[4];
  const float* g1  = (const float*)d_in[5];
  const float* be1 = (const float*)d_in[6];
  const float* W2  = (const float*)d_in[7];
  const float* b2  = (const float*)d_in[8];
  const float* g2  = (const float*)d_in[9];
  const float* be2 = (const float*)d_in[10];
  const float* Ws  = (const float*)d_in[11];
  const float* bs  = (const float*)d_in[12];
  const float* gs  = (const float*)d_in[13];
  const float* bes = (const float*)d_in[14];
  const float* gf  = (const float*)d_in[15];
  const float* bef = (const float*)d_in[16];
  const int N = in_sizes[0] / CIN;   // 50000
  const int E = in_sizes[2] / 2;     // 800000

  char* ws = (char*)d_ws;
  // layout (bytes)
  const size_t o_stats = 0;                            // 576 ll (incl K) -> pad 8192
  const size_t o_hist  = 8192;                         // N*4 -> pad 200704
  const size_t o_agg   = o_hist + 200704;              // N*256
  const size_t zeroEnd = o_agg + (size_t)N * 256;      // memset [0, zeroEnd)
  const size_t o_curs  = zeroEnd;                      // N*4 -> pad 200704
  const size_t o_coef  = o_curs + 200704;              // coef 512f + b2p 64f -> 4096
  const size_t o_W2p   = o_coef + 4096;                // 8 KB
  const size_t o_dstS  = o_W2p + 8192;                 // E*2
  const size_t o_ybuf  = o_dstS + (size_t)E * 2;       // N*128
  const size_t o_sbuf  = o_ybuf + (size_t)N * 128;     // N*128 (bf16)
  const size_t o_t1S   = o_sbuf + (size_t)N * 128;     // E*128

  long long* stats      = (long long*)(ws + o_stats);
  unsigned int* hist    = (unsigned int*)(ws + o_hist);
  unsigned int* agg     = (unsigned int*)(ws + o_agg);
  unsigned int* cursor  = (unsigned int*)(ws + o_curs);
  float* coef           = (float*)(ws + o_coef);
  float* b2p            = coef + 512;
  unsigned short* W2p   = (unsigned short*)(ws + o_W2p);
  unsigned short* dstS  = (unsigned short*)(ws + o_dstS);
  unsigned short* ybuf  = (unsigned short*)(ws + o_ybuf);
  unsigned short* sbuf  = (unsigned short*)(ws + o_sbuf);
  unsigned short* t1S   = (unsigned short*)(ws + o_t1S);

  const double invE = 1.0 / (SCALE * (double)E);
  const double invN = 1.0 / (SCALE * (double)N);
  const int total = N * 64;

  hipMemsetAsync(d_ws, 0, zeroEnd, stream);

  hipLaunchKernelGGL(k_y, dim3(1024), dim3(256), 0, stream,
                     x, W1, b1, ybuf, N, ei, hist, E);
  hipLaunchKernelGGL(k_short, dim3(1024), dim3(256), 0, stream,
                     x, Ws, bs, sbuf, stats, N);
  hipLaunchKernelGGL(k_scan, dim3(1), dim3(1024), 0, stream, hist, cursor, N);
  hipLaunchKernelGGL(k_edge1s, dim3(2048), dim3(256), 0, stream,
                     ei, pos, ybuf, W1, cursor, t1S, dstS, stats, E);
  hipLaunchKernelGGL(k_coefA, dim3(1), dim3(64), 0, stream,
                     stats, g1, be1, W2, b2, W2p, b2p, invE);
  hipLaunchKernelGGL(k_edge2, dim3(2048), dim3(256), 0, stream,
                     t1S, dstS, W2p, b2p, stats, agg, E);
  hipLaunchKernelGGL(k_aggfix, dim3(1024), dim3(256), 0, stream, agg, stats, total);
  hipLaunchKernelGGL(k_coefB, dim3(1), dim3(64), 0, stream,
                     stats, g2, be2, gs, bes, gf, bef, coef, invE, invN, N);
  hipLaunchKernelGGL(k_final, dim3((total + 255) / 256), dim3(256), 0, stream,
                     agg, sbuf, coef, (float*)d_out, total);
}

// Round 6
// 343.188 us; speedup vs baseline: 1.4726x; 1.0879x over previous
//
#include <hip/hip_runtime.h>

#define CIN 61
constexpr float EPS = 1e-5f;
constexpr double SCALE = 16777216.0;  // 2^24 fixed-point deterministic stat sums

using s16x8 = __attribute__((ext_vector_type(8))) short;
using fx4   = __attribute__((ext_vector_type(4))) float;

static __device__ __forceinline__ unsigned short f2bf(float f) {
  unsigned int u = __float_as_uint(f);
  u = (u + 0x7fffu + ((u >> 16) & 1u)) >> 16;
  return (unsigned short)u;
}
static __device__ __forceinline__ float bf2f(unsigned short h) {
  return __uint_as_float(((unsigned int)h) << 16);
}

__device__ __forceinline__ void stat_reduce(float val, float* red, long long* dst_ll) {
  int tid = threadIdx.x;
  red[tid] = val;
  __syncthreads();
  if (tid < 64) {
    float t = red[tid] + red[tid + 64] + red[tid + 128] + red[tid + 192];
    atomicAdd((unsigned long long*)&dst_ll[tid],
              (unsigned long long)(long long)((double)t * SCALE));
  }
  __syncthreads();
}

// ---- fused node pass: y = bf16(x@W1[:61]+b1), s = bf16(x@Ws+bs) + s-stats,
//      then thread-per-edge dst histogram + rank assignment (overlapped) ----
__global__ __launch_bounds__(256) void k_node(
    const float* __restrict__ x, const float* __restrict__ W1,
    const float* __restrict__ b1, const float* __restrict__ Ws,
    const float* __restrict__ bs, unsigned short* __restrict__ y,
    unsigned short* __restrict__ s_out, long long* __restrict__ stats, int N,
    const int* __restrict__ ei, unsigned int* __restrict__ hist,
    unsigned short* __restrict__ rank, int E) {
  const int tid = threadIdx.x, lane = tid & 63, wv = tid >> 6;
  float w1r[64], wsr[64];
#pragma unroll
  for (int k = 0; k < 64; ++k) {
    w1r[k] = (k < CIN) ? W1[k * 64 + lane] : 0.f;
    wsr[k] = (k < CIN) ? Ws[k * 64 + lane] : 0.f;
  }
  const float b1v = b1[lane], bsv = bs[lane];
  __shared__ float lrow[4][64];
  __shared__ float red[256];
  float ssum = 0.f, ssq = 0.f;
  const int nq = N >> 2;
  for (int q = blockIdx.x; q < nq; q += gridDim.x) {
    const int n = (q << 2) + wv;
    lrow[wv][lane] = (lane < CIN) ? x[n * CIN + lane] : 0.f;
    __syncthreads();
    float a0 = b1v, a1 = 0.f, a2 = 0.f, a3 = 0.f;
    float c0 = bsv, c1 = 0.f, c2 = 0.f, c3 = 0.f;
    const float4* rr = (const float4*)&lrow[wv][0];
#pragma unroll
    for (int k4 = 0; k4 < 16; ++k4) {
      float4 v = rr[k4];
      a0 = fmaf(v.x, w1r[4 * k4 + 0], a0);
      a1 = fmaf(v.y, w1r[4 * k4 + 1], a1);
      a2 = fmaf(v.z, w1r[4 * k4 + 2], a2);
      a3 = fmaf(v.w, w1r[4 * k4 + 3], a3);
      c0 = fmaf(v.x, wsr[4 * k4 + 0], c0);
      c1 = fmaf(v.y, wsr[4 * k4 + 1], c1);
      c2 = fmaf(v.z, wsr[4 * k4 + 2], c2);
      c3 = fmaf(v.w, wsr[4 * k4 + 3], c3);
    }
    y[(size_t)n * 64 + lane] = f2bf((a0 + a1) + (a2 + a3));
    const float sacc = (c0 + c1) + (c2 + c3);
    s_out[(size_t)n * 64 + lane] = f2bf(sacc);
    ssum += sacc;
    ssq = fmaf(sacc, sacc, ssq);
    __syncthreads();
  }
  stat_reduce(ssum, red, stats + 256);
  stat_reduce(ssq, red, stats + 320);
  // histogram + rank (within-segment order is output-invariant: max and
  // fixed-point sums are commutative, so atomic order doesn't matter)
  for (int i = blockIdx.x * 256 + tid; i < E; i += gridDim.x * 256) {
    const int dst = ei[E + i];
    rank[i] = (unsigned short)atomicAdd(&hist[dst], 1u);
  }
}

// ---- single-block exclusive scan of hist -> cursor0 (immutable) ----
__global__ __launch_bounds__(1024) void k_scan(
    const unsigned int* __restrict__ hist, unsigned int* __restrict__ cursor0, int n) {
  const int tid = threadIdx.x;
  const int per = (n + 1023) / 1024;
  const int lo = tid * per;
  const int hi = (lo + per < n) ? lo + per : n;
  unsigned int tot = 0;
  for (int i = lo; i < hi; ++i) tot += hist[i];
  const int lane = tid & 63, w = tid >> 6;
  unsigned int incl = tot;
#pragma unroll
  for (int off = 1; off < 64; off <<= 1) {
    unsigned int t = __shfl_up(incl, off);
    if (lane >= off) incl += t;
  }
  __shared__ unsigned int wsum[16];
  if (lane == 63) wsum[w] = incl;
  __syncthreads();
  unsigned int wbase = 0;
#pragma unroll
  for (int k = 0; k < 16; ++k) wbase += (k < w) ? wsum[k] : 0u;
  unsigned int run = wbase + incl - tot;  // exclusive prefix at lo
  for (int i = lo; i < hi; ++i) {
    unsigned int h = hist[i];
    cursor0[i] = run;
    run += h;
  }
}

// ---- edge pass 1: compute t1 once, stats, scatter-store bf16 row at
//      precomputed dst-sorted slot (NO atomics) ----
__global__ __launch_bounds__(256) void k_edge1s(
    const int* __restrict__ ei, const float* __restrict__ pos,
    const unsigned short* __restrict__ y, const float* __restrict__ W1,
    const unsigned int* __restrict__ cursor0, const unsigned short* __restrict__ rank,
    unsigned short* __restrict__ t1S, unsigned short* __restrict__ dstS,
    long long* __restrict__ stats, int E) {
  const int tid = threadIdx.x, lane = tid & 63, wv = tid >> 6;
  const int g = lane >> 4, c16 = lane & 15;
  float wp[3][4];
#pragma unroll
  for (int d = 0; d < 3; ++d)
#pragma unroll
    for (int i = 0; i < 4; ++i) wp[d][i] = W1[(61 + d) * 64 + 4 * c16 + i];
  float ssum[4] = {0.f, 0.f, 0.f, 0.f}, ssq[4] = {0.f, 0.f, 0.f, 0.f};
  const int ngrp = E >> 2;  // E % 4 == 0
  const int nw = gridDim.x * 4;
  for (int q = blockIdx.x * 4 + wv; q < ngrp; q += nw) {
    const int e = (q << 2) + g;
    const int src = ei[e], dst = ei[E + e];
    float pv = 0.f;
    if (c16 < 3) pv = pos[src * 3 + c16] - pos[dst * 3 + c16];
    unsigned int offv = 0;
    if (c16 == 0) offv = cursor0[dst] + rank[e];
    const float p0 = __shfl(pv, g * 16 + 0);
    const float p1 = __shfl(pv, g * 16 + 1);
    const float p2 = __shfl(pv, g * 16 + 2);
    const unsigned int off = __shfl(offv, g * 16);
    const ushort4 yv = *(const ushort4*)(y + (size_t)src * 64 + 4 * c16);
    const unsigned short* yc = (const unsigned short*)&yv;
    float t[4];
#pragma unroll
    for (int i = 0; i < 4; ++i) {
      float v = bf2f(yc[i]);
      v = fmaf(p0, wp[0][i], v);
      v = fmaf(p1, wp[1][i], v);
      v = fmaf(p2, wp[2][i], v);
      v = fmaxf(v, 0.f);
      t[i] = v;
      ssum[i] += v;
      ssq[i] = fmaf(v, v, ssq[i]);
    }
    ushort4 tb;
    tb.x = f2bf(t[0]); tb.y = f2bf(t[1]); tb.z = f2bf(t[2]); tb.w = f2bf(t[3]);
    *(ushort4*)(t1S + (size_t)off * 64 + 4 * c16) = tb;
    if (c16 == 0) dstS[off] = (unsigned short)dst;
  }
#pragma unroll
  for (int i = 0; i < 4; ++i) {
    ssum[i] += __shfl_xor(ssum[i], 16); ssum[i] += __shfl_xor(ssum[i], 32);
    ssq[i]  += __shfl_xor(ssq[i], 16);  ssq[i]  += __shfl_xor(ssq[i], 32);
  }
  __shared__ float sred[2][64];
  if (tid < 128) ((float*)sred)[tid] = 0.f;
  __syncthreads();
  if (g == 0) {
#pragma unroll
    for (int i = 0; i < 4; ++i) {
      atomicAdd(&sred[0][4 * c16 + i], ssum[i]);
      atomicAdd(&sred[1][4 * c16 + i], ssq[i]);
    }
  }
  __syncthreads();
  if (tid < 64) {
    atomicAdd((unsigned long long*)&stats[0 + tid],
              (unsigned long long)(long long)((double)sred[0][tid] * SCALE));
    atomicAdd((unsigned long long*)&stats[64 + tid],
              (unsigned long long)(long long)((double)sred[1][tid] * SCALE));
  }
}

// ---- BN1 coef + fold into W2 ----
__global__ void k_coefA(const long long* __restrict__ stats,
                        const float* __restrict__ g1, const float* __restrict__ be1,
                        const float* __restrict__ W2, const float* __restrict__ b2,
                        unsigned short* __restrict__ W2p, float* __restrict__ b2p,
                        double invE) {
  const int c = threadIdx.x;
  __shared__ float a1s[64], c1s[64];
  double m = (double)stats[c] * invE;
  double v = (double)stats[64 + c] * invE - m * m;
  float a = g1[c] * rsqrtf((float)v + EPS);
  a1s[c] = a;
  c1s[c] = fmaf(-(float)m, a, be1[c]);
  __syncthreads();
  float acc = b2[c];
  for (int k = 0; k < 64; ++k) {
    const float w = W2[k * 64 + c];
    acc = fmaf(c1s[k], w, acc);
    W2p[k * 64 + c] = f2bf(a1s[k] * w);
  }
  b2p[c] = acc;
}

// ---- edge pass 2: contiguous streaming MFMA + stats + chunk-owned segment max.
//      Wave owns 128 consecutive rows: interior segments -> plain store,
//      chunk-boundary runs -> atomicMax (~2/lane/chunk). ----
__global__ __launch_bounds__(256) void k_edge2(
    const unsigned short* __restrict__ t1S, const unsigned short* __restrict__ dstS,
    const unsigned short* __restrict__ W2p, const float* __restrict__ b2p,
    long long* __restrict__ stats, unsigned int* __restrict__ agg, int E) {
  const int tid = threadIdx.x, lane = tid & 63, wv = tid >> 6;
  const int l15 = lane & 15, lg = lane >> 4;
  s16x8 bF[4][2];
#pragma unroll
  for (int t = 0; t < 4; ++t) {
    const int col = l15 + 16 * t;
#pragma unroll
    for (int s = 0; s < 2; ++s)
#pragma unroll
      for (int i = 0; i < 8; ++i)
        bF[t][s][i] = (short)W2p[(s * 32 + lg * 8 + i) * 64 + col];
  }
  float bias[4];
#pragma unroll
  for (int t = 0; t < 4; ++t) bias[t] = b2p[l15 + 16 * t];
  __shared__ float ld2[4][16][68];  // pad 68: <=2-way bank aliasing (free)
  __shared__ int ldd[4][16];
  float ssum[4] = {0.f, 0.f, 0.f, 0.f}, ssq[4] = {0.f, 0.f, 0.f, 0.f};
  const int nchunk = E >> 7;  // 128 rows per chunk (E % 128 == 0)
  const int nw = gridDim.x * 4;
  for (int ch = blockIdx.x * 4 + wv; ch < nchunk; ch += nw) {
    int cur = -1;
    float m = 0.f;
    bool inside = false;
    const int row0 = ch << 7;
#pragma unroll 1
    for (int t8 = 0; t8 < 8; ++t8) {
      const int rbase = row0 + (t8 << 4);
      const unsigned short* arow = t1S + (size_t)(rbase + l15) * 64 + lg * 8;
      const s16x8 aF0 = *(const s16x8*)(arow);
      const s16x8 aF1 = *(const s16x8*)(arow + 32);
      if (lg == 0) ldd[wv][l15] = (int)dstS[rbase + l15];
      fx4 acc[4];
#pragma unroll
      for (int t = 0; t < 4; ++t) {
        acc[t][0] = bias[t]; acc[t][1] = bias[t];
        acc[t][2] = bias[t]; acc[t][3] = bias[t];
      }
#pragma unroll
      for (int t = 0; t < 4; ++t) {
        acc[t] = __builtin_amdgcn_mfma_f32_16x16x32_bf16(aF0, bF[t][0], acc[t], 0, 0, 0);
        acc[t] = __builtin_amdgcn_mfma_f32_16x16x32_bf16(aF1, bF[t][1], acc[t], 0, 0, 0);
      }
#pragma unroll
      for (int t = 0; t < 4; ++t) {
        const int col = l15 + 16 * t;
#pragma unroll
        for (int j = 0; j < 4; ++j) {
          const float v = fmaxf(acc[t][j], 0.f);
          ssum[t] += v;
          ssq[t] = fmaf(v, v, ssq[t]);
          ld2[wv][lg * 4 + j][col] = v;
        }
      }
      __builtin_amdgcn_wave_barrier();  // order LDS writes before reads
#pragma unroll
      for (int r = 0; r < 16; ++r) {
        const int d = ldd[wv][r];
        const float v = ld2[wv][r][lane];
        if (d == cur) {
          m = fmaxf(m, v);
        } else {
          if (cur >= 0) {
            const unsigned int enc = __float_as_uint(m) | 0x80000000u;
            if (inside) agg[(size_t)cur * 64 + lane] = enc;       // complete segment
            else atomicMax(&agg[(size_t)cur * 64 + lane], enc);   // boundary carry-in
          }
          cur = d;
          m = v;
          inside = (t8 > 0) || (r > 0);  // run starts strictly inside chunk
        }
      }
      __builtin_amdgcn_wave_barrier();  // order reads before next tile's writes
    }
    if (cur >= 0)  // final run may continue into next chunk
      atomicMax(&agg[(size_t)cur * 64 + lane], __float_as_uint(m) | 0x80000000u);
  }
#pragma unroll
  for (int t = 0; t < 4; ++t) {
    ssum[t] += __shfl_xor(ssum[t], 16); ssum[t] += __shfl_xor(ssum[t], 32);
    ssq[t]  += __shfl_xor(ssq[t], 16);  ssq[t]  += __shfl_xor(ssq[t], 32);
  }
  __shared__ float sred[2][64];
  if (tid < 128) ((float*)sred)[tid] = 0.f;
  __syncthreads();
  if (lg == 0) {
#pragma unroll
    for (int t = 0; t < 4; ++t) {
      atomicAdd(&sred[0][l15 + 16 * t], ssum[t]);
      atomicAdd(&sred[1][l15 + 16 * t], ssq[t]);
    }
  }
  __syncthreads();
  if (tid < 64) {
    atomicAdd((unsigned long long*)&stats[128 + tid],
              (unsigned long long)(long long)((double)sred[0][tid] * SCALE));
    atomicAdd((unsigned long long*)&stats[192 + tid],
              (unsigned long long)(long long)((double)sred[1][tid] * SCALE));
  }
}

// ---- stats of raw maxima over nonempty nodes + nonempty count (flag bit) ----
__global__ __launch_bounds__(256) void k_aggfix(
    const unsigned int* __restrict__ agg, long long* __restrict__ stats, int total) {
  const int tid = threadIdx.x;
  __shared__ float red[256];
  float ssum = 0.f, ssq = 0.f, kcf = 0.f;
  const int step = gridDim.x * 256;
  for (int i = blockIdx.x * 256 + tid; i < total; i += step) {
    const unsigned int u = agg[i];
    if (u >> 31) {
      const float v = __uint_as_float(u & 0x7fffffffu);
      ssum += v;
      ssq = fmaf(v, v, ssq);
      if ((i & 63) == 0) kcf += 1.f;
    }
  }
  stat_reduce(ssum, red, stats + 384);
  stat_reduce(ssq, red, stats + 448);
  stat_reduce(kcf, red, stats + 512);
}

// ---- all remaining BN coefs, composed for the final pass ----
// coef: [0)=Aagg, [64)=Cagg, [128)=CE(empty), [192)=aS, [256)=cS
__global__ void k_coefB(const long long* __restrict__ stats,
                        const float* __restrict__ g2, const float* __restrict__ be2,
                        const float* __restrict__ gs, const float* __restrict__ bes,
                        const float* __restrict__ gf, const float* __restrict__ bef,
                        float* __restrict__ coef, double invE, double invN, int N) {
  const int c = threadIdx.x;
  double m2 = (double)stats[128 + c] * invE;
  double v2 = (double)stats[192 + c] * invE - m2 * m2;
  float a2 = g2[c] * rsqrtf((float)v2 + EPS);
  float c2 = fmaf(-(float)m2, a2, be2[c]);
  double mS = (double)stats[256 + c] * invN;
  double vS = (double)stats[320 + c] * invN - mS * mS;
  float aS = gs[c] * rsqrtf((float)vS + EPS);
  float cS = fmaf(-(float)mS, aS, bes[c]);
  double su = (double)stats[384 + c] / SCALE;
  double qu = (double)stats[448 + c] / SCALE;
  double K  = (double)stats[512] / SCALE;
  double sv = (double)a2 * su + (double)c2 * K;
  double qv = (double)a2 * a2 * qu + 2.0 * a2 * c2 * su + (double)c2 * c2 * K;
  double mv = sv / N;
  double vv = qv / N - mv * mv;
  float aF = gf[c] * rsqrtf((float)vv + EPS);
  float cF = fmaf(-(float)mv, aF, bef[c]);
  coef[c]       = aF * a2;
  coef[64 + c]  = fmaf(aF, c2, cF);
  coef[128 + c] = cF;
  coef[192 + c] = aS;
  coef[256 + c] = cS;
}

__global__ __launch_bounds__(256) void k_final(
    const unsigned int* __restrict__ agg, const unsigned short* __restrict__ sbuf,
    const float* __restrict__ coef, float* __restrict__ out, int total) {
  int i = blockIdx.x * 256 + threadIdx.x;
  if (i >= total) return;
  const int c = i & 63;
  const unsigned int u = agg[i];
  float base;
  if (u >> 31)
    base = fmaf(coef[c], __uint_as_float(u & 0x7fffffffu), coef[64 + c]);
  else
    base = coef[128 + c];
  const float sv = fmaf(coef[192 + c], bf2f(sbuf[i]), coef[256 + c]);
  out[i] = fmaxf(base + sv, 0.f);
}

extern "C" void kernel_launch(void* const* d_in, const int* in_sizes, int n_in,
                              void* d_out, int out_size, void* d_ws, size_t ws_size,
                              hipStream_t stream) {
  const float* x   = (const float*)d_in[0];
  const float* pos = (const float*)d_in[1];
  const int*   ei  = (const int*)d_in[2];
  const float* W1  = (const float*)d_in[3];
  const float* b1  = (const float*)d_in[4];
  const float* g1  = (const float*)d_in[5];
  const float* be1 = (const float*)d_in[6];
  const float* W2  = (const float*)d_in[7];
  const float* b2  = (const float*)d_in[8];
  const float* g2  = (const float*)d_in[9];
  const float* be2 = (const float*)d_in[10];
  const float* Ws  = (const float*)d_in[11];
  const float* bs  = (const float*)d_in[12];
  const float* gs  = (const float*)d_in[13];
  const float* bes = (const float*)d_in[14];
  const float* gf  = (const float*)d_in[15];
  const float* bef = (const float*)d_in[16];
  const int N = in_sizes[0] / CIN;   // 50000
  const int E = in_sizes[2] / 2;     // 800000

  char* ws = (char*)d_ws;
  // layout (bytes)
  const size_t o_stats = 0;                            // 576 ll -> pad 8192
  const size_t o_hist  = 8192;                         // N*4 -> pad 200704
  const size_t o_agg   = o_hist + 200704;              // N*256
  const size_t zeroEnd = o_agg + (size_t)N * 256;      // memset [0, zeroEnd)
  const size_t o_curs0 = zeroEnd;                      // N*4 -> pad 200704
  const size_t o_coef  = o_curs0 + 200704;             // coef 512f + b2p 64f -> 4096
  const size_t o_W2p   = o_coef + 4096;                // 8 KB
  const size_t o_rank  = o_W2p + 8192;                 // E*2
  const size_t o_dstS  = o_rank + (size_t)E * 2;       // E*2
  const size_t o_ybuf  = o_dstS + (size_t)E * 2;       // N*128
  const size_t o_sbuf  = o_ybuf + (size_t)N * 128;     // N*128
  const size_t o_t1S   = o_sbuf + (size_t)N * 128;     // E*128

  long long* stats      = (long long*)(ws + o_stats);
  unsigned int* hist    = (unsigned int*)(ws + o_hist);
  unsigned int* agg     = (unsigned int*)(ws + o_agg);
  unsigned int* cursor0 = (unsigned int*)(ws + o_curs0);
  float* coef           = (float*)(ws + o_coef);
  float* b2p            = coef + 512;
  unsigned short* W2p   = (unsigned short*)(ws + o_W2p);
  unsigned short* rank  = (unsigned short*)(ws + o_rank);
  unsigned short* dstS  = (unsigned short*)(ws + o_dstS);
  unsigned short* ybuf  = (unsigned short*)(ws + o_ybuf);
  unsigned short* sbuf  = (unsigned short*)(ws + o_sbuf);
  unsigned short* t1S   = (unsigned short*)(ws + o_t1S);

  const double invE = 1.0 / (SCALE * (double)E);
  const double invN = 1.0 / (SCALE * (double)N);
  const int total = N * 64;

  hipMemsetAsync(d_ws, 0, zeroEnd, stream);

  hipLaunchKernelGGL(k_node, dim3(1024), dim3(256), 0, stream,
                     x, W1, b1, Ws, bs, ybuf, sbuf, stats, N, ei, hist, rank, E);
  hipLaunchKernelGGL(k_scan, dim3(1), dim3(1024), 0, stream, hist, cursor0, N);
  hipLaunchKernelGGL(k_edge1s, dim3(2048), dim3(256), 0, stream,
                     ei, pos, ybuf, W1, cursor0, rank, t1S, dstS, stats, E);
  hipLaunchKernelGGL(k_coefA, dim3(1), dim3(64), 0, stream,
                     stats, g1, be1, W2, b2, W2p, b2p, invE);
  {
    const int nchunk = E >> 7;
    const int blocks = (nchunk + 3) / 4;
    hipLaunchKernelGGL(k_edge2, dim3(blocks), dim3(256), 0, stream,
                       t1S, dstS, W2p, b2p, stats, agg, E);
  }
  hipLaunchKernelGGL(k_aggfix, dim3(1024), dim3(256), 0, stream, agg, stats, total);
  hipLaunchKernelGGL(k_coefB, dim3(1), dim3(64), 0, stream,
                     stats, g2, be2, gs, bes, gf, bef, coef, invE, invN, N);
  hipLaunchKernelGGL(k_final, dim3((total + 255) / 256), dim3(256), 0, stream,
                     agg, sbuf, coef, (float*)d_out, total);
}